// Round 5
// baseline (852.163 us; speedup 1.0000x reference)
//
#include <hip/hip_runtime.h>
#include <hip/hip_bf16.h>

// EmbeddingCrossAttention on MI355X (gfx950). f32 in/out, bf16 MFMA compute.
//
// softmax over single kv slot == 1  =>  ctx = v  =>  everything is affine:
//   t = text@Wt^T+bt ; a = audio@Wa^T+ba
//   t_ctx = a@Wvo^T + bvo            (Wvo = Wo.Wv, bvo = Wo.bv + bo)
//   logit_t = t@Wgt1^T + a@(Wgt2.Wvo)^T + (bgt + Wgt2.bvo)
//   refined_t = g*t + (1-g)*t_ctx, g = sigmoid(logit_t)   (audio swapped)
//
// Round-9 (post-mortem r8: fused 285us @ MfmaUtil 32 / VALU 39 / Occ 22.6;
// MFMA-busy ~91us of 285 -> structure-bound, not compute-bound):
//   B-DIRECT: weight (B) fragments are read straight global->VGPR from the
//   L2-resident weight panels (m-swizzle pins each n-panel's weights in one
//   XCD's L2; per-block B has zero cross-wave reuse, LDS staging was pure
//   overhead). Only A (the X stream, shared by 2 waves) stays in LDS.
//     - per-tile gl_lds 6->2, ds_read 12->4, LDS 48->24KB (3-buf A)
//     - ONE barrier per K-tile (3-buf rotation, write/read distance 2 mod 3
//       — scheme proven in r8's gemm_bt2)
//     - B loads issued PRE-barrier into persistent frag regs: L2 latency
//       hides under WAITV+barrier+A-ds_reads. Counted vmcnt for the mixed
//       queue: ph1 WAITV(6)=A(t+1)*2+B(t)*4, ph2 WAITV(10), never 0 mid-loop.
//   Applied to fused_gate AND gemm_bt2 (projections + weight folds).

typedef __attribute__((ext_vector_type(8))) short short8;
typedef __attribute__((ext_vector_type(4))) float floatx4;

#define WAITV(N) asm volatile("s_waitcnt vmcnt(" #N ")" ::: "memory")
__device__ __forceinline__ void blockbar() {
  asm volatile("" ::: "memory");
  __builtin_amdgcn_s_barrier();
  asm volatile("" ::: "memory");
}

__device__ __forceinline__ float bf2f(__hip_bfloat16 x) { return __bfloat162float(x); }

__device__ __forceinline__ void gl_lds16(const void* g, void* l) {
  __builtin_amdgcn_global_load_lds(
      (const __attribute__((address_space(1))) unsigned int*)g,
      (__attribute__((address_space(3))) unsigned int*)l,
      16, 0, 0);
}

// XCD-aware block swizzle: same-m blocks share lid%8 -> same XCD, 8 lids apart
// -> A-tile stays L2-resident across its n-sweep; n-panel weights pinned per XCD.
__device__ __forceinline__ void swizzle_mn(int& m_idx, int& n_idx) {
  const int lid = blockIdx.y * 8 + blockIdx.x;
  m_idx = (lid >> 6) * 8 + (lid & 7);
  n_idx = (lid >> 3) & 7;
}

// ---- 9-job strided f32 -> bf16 convert; 1 block per row ----
struct CvtJob { const float* src; __hip_bfloat16* dst; int sld, dld, cols4, rowbase; };
struct CvtJobs { CvtJob j[9]; };

__global__ __launch_bounds__(256)
void cvt9_kernel(CvtJobs a) {
  const int r = blockIdx.x;
  int ji = 0;
#pragma unroll
  for (int i = 1; i < 9; ++i) ji += (r >= a.j[i].rowbase) ? 1 : 0;
  const CvtJob J = a.j[ji];
  const int rr = r - J.rowbase;
  const int c4 = threadIdx.x;
  if (c4 >= J.cols4) return;
  const float4 v = *(const float4*)(J.src + (size_t)rr * J.sld + c4 * 4);
  union { __hip_bfloat16 h[4]; uint2 u; } o;
  o.h[0] = __float2bfloat16(v.x);
  o.h[1] = __float2bfloat16(v.y);
  o.h[2] = __float2bfloat16(v.z);
  o.h[3] = __float2bfloat16(v.w);
  *(uint2*)(J.dst + (size_t)rr * J.dld + c4 * 4) = o.u;
}

// Transposed convert: dst[c][r] = bf16(src[r][c]), R=C=1024 (f32 in).
__global__ __launch_bounds__(256)
void cvt_t_kernel(const float* __restrict__ src, __hip_bfloat16* __restrict__ dst,
                  int R, int C) {
  __shared__ float tile[32][33];
  const int tx = threadIdx.x, ty = threadIdx.y;  // block (32, 8)
  const int bx = blockIdx.x * 32, by = blockIdx.y * 32;
#pragma unroll
  for (int i = 0; i < 32; i += 8)
    tile[ty + i][tx] = src[(size_t)(by + ty + i) * C + bx + tx];
  __syncthreads();
#pragma unroll
  for (int i = 0; i < 32; i += 8)
    dst[(size_t)(bx + ty + i) * R + by + tx] = __float2bfloat16(tile[tx][ty + i]);
}

// bf16 1024x1024 transpose: dst[c][r] = src[r][c].
__global__ __launch_bounds__(256)
void tr_bf16_kernel(const __hip_bfloat16* __restrict__ src,
                    __hip_bfloat16* __restrict__ dst) {
  __shared__ __hip_bfloat16 tile[32][33];
  const int tx = threadIdx.x, ty = threadIdx.y;  // block (32, 8)
  const int bx = blockIdx.x * 32, by = blockIdx.y * 32;
#pragma unroll
  for (int i = 0; i < 32; i += 8)
    tile[ty + i][tx] = src[(size_t)(by + ty + i) * 1024 + bx + tx];
  __syncthreads();
#pragma unroll
  for (int i = 0; i < 32; i += 8)
    dst[(size_t)(bx + ty + i) * 1024 + by + tx] = tile[tx][ty + i];
}

// y[r] = sum_k W[r*ld + coff + k] * x[k] + b[r],  K = 1024. 4 rows/block.
__global__ __launch_bounds__(256)
void mv_kernel(const float* __restrict__ W, int ld, int coff,
               const float* __restrict__ x, const float* __restrict__ b,
               float* __restrict__ y) {
  const int lane = threadIdx.x & 63;
  const int row = blockIdx.x * 4 + (threadIdx.x >> 6);
  float acc = 0.f;
  for (int k = lane; k < 1024; k += 64)
    acc += W[(size_t)row * ld + coff + k] * x[k];
#pragma unroll
  for (int off = 32; off > 0; off >>= 1) acc += __shfl_down(acc, off);
  if (lane == 0) y[row] = acc + b[row];
}

// Two mv jobs in one launch (both ld=2048, coff=1024, x=bvo). blockIdx.y picks.
__global__ __launch_bounds__(256)
void mv2_kernel(const float* __restrict__ W0, const float* __restrict__ W1,
                const float* __restrict__ x,
                const float* __restrict__ b0, const float* __restrict__ b1,
                float* __restrict__ y0, float* __restrict__ y1) {
  const float* W = blockIdx.y ? W1 : W0;
  const float* b = blockIdx.y ? b1 : b0;
  float* y = blockIdx.y ? y1 : y0;
  const int lane = threadIdx.x & 63;
  const int row = blockIdx.x * 4 + (threadIdx.x >> 6);
  float acc = 0.f;
  for (int k = lane; k < 1024; k += 64)
    acc += W[(size_t)row * 2048 + 1024 + k] * x[k];
#pragma unroll
  for (int off = 32; off > 0; off >>= 1) acc += __shfl_down(acc, off);
  if (lane == 0) y[row] = acc + b[row];
}

// C = A @ W^T (+bias), bf16 out. Two jobs split on m_idx. BK=32; A staged in
// 3-buf LDS (1 barrier/tile, counted vmcnt); B fragments read direct from
// global (L2-resident weight panel), issued pre-barrier. K%32==0, K/32>=2.
struct GemmJob {
  const __hip_bfloat16* A; const __hip_bfloat16* W;
  const float* bias; __hip_bfloat16* C; int K; int ldc; int coff;
};

__global__ __launch_bounds__(256)
void gemm_bt2_kernel(GemmJob j0, GemmJob j1, int mSplit) {
  constexpr int BK = 32;
  __shared__ __align__(16) __hip_bfloat16 lA[3 * 128 * BK];   // 24 KB

  const int tid  = threadIdx.x;
  const int lane = tid & 63;
  const int wave = tid >> 6;
  const int wm = wave & 1;
  const int wn = wave >> 1;
  int m_idx, n_idx;
  swizzle_mn(m_idx, n_idx);
  const bool sec = m_idx >= mSplit;
  const GemmJob J = sec ? j1 : j0;
  const int m0 = (sec ? m_idx - mSplit : m_idx) * 128;
  const int n0 = n_idx * 128;
  const int K = J.K;

  floatx4 acc[4][4];
#pragma unroll
  for (int i = 0; i < 4; ++i)
#pragma unroll
    for (int j = 0; j < 4; ++j) {
      floatx4 z = {0.f, 0.f, 0.f, 0.f};
      acc[i][j] = z;
    }

  const int srow  = tid >> 2;
  const int sc_sw = ((tid & 3) ^ (srow & 3)) * 8;   // pre-swizzled global col (A staging)
  const int fr  = lane & 15;
  const int fqs = (((lane >> 4) ^ (fr & 3))) * 8;   // swizzled LDS read col (A frags)
  const int fqg = (lane >> 4) * 8;                  // plain col for direct B reads

  const __hip_bfloat16* pA = J.A + (size_t)(m0 + srow) * K + sc_sw;
  const __hip_bfloat16* Wb = J.W + (size_t)n0 * K;  // uniform base (SGPR)
  int ob = (wn * 64 + fr) * K + fqg;                // per-lane B elem offset, +=32/tile
  const size_t SR = (size_t)64 * K;

  int sOff = 0, cOff = 0;
  auto stageA = [&]() {
    gl_lds16(pA,      (char*)lA + sOff + tid * 16);
    gl_lds16(pA + SR, (char*)lA + sOff + 4096 + tid * 16);
    pA += BK;
    sOff = (sOff == 16384) ? 0 : sOff + 8192;
  };

  short8 bfr[4];
  auto loadB = [&]() {
#pragma unroll
    for (int j = 0; j < 4; ++j)
      bfr[j] = *(const short8*)(Wb + j * 16 * K + ob);
    ob += 32;
  };

  auto compute = [&]() {
    const short* sA = (const short*)((const char*)lA + cOff);
    short8 af[4];
#pragma unroll
    for (int i = 0; i < 4; ++i)
      af[i] = *(const short8*)(sA + (wm * 64 + i * 16 + fr) * BK + fqs);
#pragma unroll
    for (int i = 0; i < 4; ++i)
#pragma unroll
      for (int j = 0; j < 4; ++j)
        acc[i][j] = __builtin_amdgcn_mfma_f32_16x16x32_bf16(af[i], bfr[j], acc[i][j], 0, 0, 0);
    cOff = (cOff == 16384) ? 0 : cOff + 8192;
  };

  const int NT = K / BK;
  stageA();                            // tile 0
  for (int t = 0; t < NT - 1; ++t) {
    stageA();                          // A(t+1): 2 gl_lds in flight
    loadB();                           // B(t): 4 reg loads, pre-barrier
    WAITV(6);                          // drain A(t); keep A(t+1)+B(t)
    blockbar();
    compute();
  }
  loadB();                             // B(NT-1)
  WAITV(4);                            // drain A(NT-1); keep B
  blockbar();
  compute();

  const int col = lane & 15;
  const int rq  = (lane >> 4) * 4;
#pragma unroll
  for (int j = 0; j < 4; ++j) {
    const int n = n0 + wn * 64 + j * 16 + col;
    const float bv = J.bias ? J.bias[n] : 0.f;
#pragma unroll
    for (int i = 0; i < 4; ++i)
#pragma unroll
      for (int r = 0; r < 4; ++r) {
        const int m = m0 + wm * 64 + i * 16 + rq + r;
        J.C[(size_t)m * J.ldc + J.coff + n] = __float2bfloat16(acc[i][j][r] + bv);
      }
  }
}

// Fused ctx + gate, BOTH modalities in one dispatch (m_idx >= 128 -> audio):
//   phase 1 (32 tiles): accL += Xs @ Wg1^T
//   phase 2 (32 tiles): accL += Xo @ Wg2vo^T ; accC += Xo @ Wvo^T
//   out[m,n] = g*Xs[m,n] + (1-g)*(accC+bvo),  g = sigmoid(accL+bg)
// A in 3-buf LDS (1 barrier/tile, counted vmcnt); B/C weights direct from L2.
__global__ __launch_bounds__(256)
void fused_gate_kernel(const __hip_bfloat16* __restrict__ Xt,
                       const __hip_bfloat16* __restrict__ Xa,
                       const __hip_bfloat16* __restrict__ Wg1t,
                       const __hip_bfloat16* __restrict__ Wg1a,
                       const __hip_bfloat16* __restrict__ G2vo,   // 2048 x 1024
                       const __hip_bfloat16* __restrict__ Wvo,    // 1024 x 1024
                       const float* __restrict__ bgt,
                       const float* __restrict__ bga,
                       const float* __restrict__ bvo,
                       float* __restrict__ out) {
  constexpr int BK = 32;
  __shared__ __align__(16) __hip_bfloat16 lA[3 * 128 * BK];   // 24 KB

  const int tid  = threadIdx.x;
  const int lane = tid & 63;
  const int wave = tid >> 6;
  const int wm = wave & 1;
  const int wn = wave >> 1;
  int m_idx, n_idx;
  swizzle_mn(m_idx, n_idx);
  const bool aud = m_idx >= 128;
  const int m0 = (m_idx & 127) * 128;
  const int n0 = n_idx * 128;

  const size_t M1 = 1024ull * 1024;
  const __hip_bfloat16* Xs   = aud ? Xa : Xt;
  const __hip_bfloat16* Xo   = aud ? Xt : Xa;
  const __hip_bfloat16* Wg1B = (aud ? Wg1a : Wg1t) + (size_t)n0 * 1024;
  const __hip_bfloat16* Wg2B = G2vo + (aud ? M1 : 0) + (size_t)n0 * 1024;
  const __hip_bfloat16* WvoB = Wvo + (size_t)n0 * 1024;
  const float* bg = aud ? bga : bgt;
  float* po = out + (aud ? (size_t)16384 * 1024 : 0);

  floatx4 accL[4][4], accC[4][4];
#pragma unroll
  for (int i = 0; i < 4; ++i)
#pragma unroll
    for (int j = 0; j < 4; ++j) {
      floatx4 z = {0.f, 0.f, 0.f, 0.f};
      accL[i][j] = z;
      accC[i][j] = z;
    }

  const int srow  = tid >> 2;
  const int sc_sw = ((tid & 3) ^ (srow & 3)) * 8;
  const int fr  = lane & 15;
  const int fqs = (((lane >> 4) ^ (fr & 3))) * 8;
  const int fqg = (lane >> 4) * 8;

  const __hip_bfloat16* pAs = Xs + (size_t)(m0 + srow) * 1024 + sc_sw;
  const __hip_bfloat16* pAo = Xo + (size_t)(m0 + srow) * 1024 + sc_sw;
  const size_t SR = (size_t)64 * 1024;

  int sOff = 0, cOff = 0;
  auto stage1 = [&]() {
    gl_lds16(pAs,      (char*)lA + sOff + tid * 16);
    gl_lds16(pAs + SR, (char*)lA + sOff + 4096 + tid * 16);
    pAs += BK;
    sOff = (sOff == 16384) ? 0 : sOff + 8192;
  };
  auto stage2 = [&]() {
    gl_lds16(pAo,      (char*)lA + sOff + tid * 16);
    gl_lds16(pAo + SR, (char*)lA + sOff + 4096 + tid * 16);
    pAo += BK;
    sOff = (sOff == 16384) ? 0 : sOff + 8192;
  };

  int ob1 = (wn * 64 + fr) * 1024 + fqg;   // B offset, phase 1
  int ob2 = ob1;                           // B offset, phase 2

  short8 bfr[4], cfr[4];
  auto loadB1 = [&]() {
#pragma unroll
    for (int j = 0; j < 4; ++j)
      bfr[j] = *(const short8*)(Wg1B + j * 16384 + ob1);
    ob1 += 32;
  };
  auto loadB2 = [&]() {
#pragma unroll
    for (int j = 0; j < 4; ++j) {
      bfr[j] = *(const short8*)(Wg2B + j * 16384 + ob2);
      cfr[j] = *(const short8*)(WvoB + j * 16384 + ob2);
    }
    ob2 += 32;
  };

  auto comp1 = [&]() {
    const short* sA = (const short*)((const char*)lA + cOff);
    short8 af[4];
#pragma unroll
    for (int i = 0; i < 4; ++i)
      af[i] = *(const short8*)(sA + (wm * 64 + i * 16 + fr) * BK + fqs);
#pragma unroll
    for (int i = 0; i < 4; ++i)
#pragma unroll
      for (int j = 0; j < 4; ++j)
        accL[i][j] = __builtin_amdgcn_mfma_f32_16x16x32_bf16(af[i], bfr[j], accL[i][j], 0, 0, 0);
    cOff = (cOff == 16384) ? 0 : cOff + 8192;
  };
  auto comp2 = [&]() {
    const short* sA = (const short*)((const char*)lA + cOff);
    short8 af[4];
#pragma unroll
    for (int i = 0; i < 4; ++i)
      af[i] = *(const short8*)(sA + (wm * 64 + i * 16 + fr) * BK + fqs);
#pragma unroll
    for (int i = 0; i < 4; ++i)
#pragma unroll
      for (int j = 0; j < 4; ++j) {
        accL[i][j] = __builtin_amdgcn_mfma_f32_16x16x32_bf16(af[i], bfr[j], accL[i][j], 0, 0, 0);
        accC[i][j] = __builtin_amdgcn_mfma_f32_16x16x32_bf16(af[i], cfr[j], accC[i][j], 0, 0, 0);
      }
    cOff = (cOff == 16384) ? 0 : cOff + 8192;
  };

  // phase 1: tiles 0..31
  stage1();                              // tile 0
  for (int t = 0; t < 31; ++t) {
    stage1();                            // A(t+1)
    loadB1();                            // B(t), pre-barrier
    WAITV(6);                            // drain A(t); keep A(t+1)2 + B(t)4
    blockbar();
    comp1();
  }
  // boundary: prefetch first phase-2 A-tile, finish last phase-1 tile
  stage2();                              // tile 32 (A = Xo)
  loadB1();                              // B(31)
  WAITV(6);
  blockbar();
  comp1();                               // tile 31
  // phase 2: tiles 32..63
  for (int t = 0; t < 31; ++t) {
    stage2();                            // A(t+1)
    loadB2();                            // B+C(t): 8 reg loads
    WAITV(10);                           // drain A(t); keep A(t+1)2 + BC(t)8
    blockbar();
    comp2();
  }
  loadB2();                              // B+C(63)
  WAITV(8);                              // drain A(63); keep BC(63)
  blockbar();
  comp2();                               // tile 63

  // epilogue: D mapping col = lane&15, row = (lane>>4)*4 + reg
  const int col = lane & 15;
  const int rq  = (lane >> 4) * 4;
#pragma unroll
  for (int j = 0; j < 4; ++j) {
    const int n = n0 + wn * 64 + j * 16 + col;
    const float bgv = bg[n];
    const float bcv = bvo[n];
#pragma unroll
    for (int i = 0; i < 4; ++i)
#pragma unroll
      for (int r = 0; r < 4; ++r) {
        const int m = m0 + wm * 64 + i * 16 + rq + r;
        const size_t idx = (size_t)m * 1024 + n;
        const float lg = accL[i][j][r] + bgv;
        const float cv = accC[i][j][r] + bcv;
        const float xv = bf2f(Xs[idx]);
        const float g = 1.f / (1.f + __expf(-lg));
        po[idx] = g * xv + (1.f - g) * cv;
      }
  }
}

extern "C" void kernel_launch(void* const* d_in, const int* in_sizes, int n_in,
                              void* d_out, int out_size, void* d_ws, size_t ws_size,
                              hipStream_t stream) {
  (void)in_sizes; (void)n_in; (void)out_size; (void)ws_size;

  const float* text  = (const float*)d_in[0];
  const float* audio = (const float*)d_in[1];
  const float* Wt  = (const float*)d_in[2];
  const float* bt  = (const float*)d_in[3];
  const float* Wa  = (const float*)d_in[4];
  const float* ba  = (const float*)d_in[5];
  // d_in[6..9] = Wq,bq,Wk,bk: dead (softmax over single kv slot == 1)
  const float* Wv  = (const float*)d_in[10];
  const float* bv  = (const float*)d_in[11];
  const float* Wo  = (const float*)d_in[12];
  const float* bo  = (const float*)d_in[13];
  const float* Wgt = (const float*)d_in[14];
  const float* bgt = (const float*)d_in[15];
  const float* Wga = (const float*)d_in[16];
  const float* bga = (const float*)d_in[17];

  const size_t BE = 16384ull * 1024;
  const size_t M1 = 1024ull * 1024;
  float* out = (float*)d_out;

  // ws (persistent): ~79.5 MB (< 92 MB proven-safe budget)
  __hip_bfloat16* p = (__hip_bfloat16*)d_ws;
  __hip_bfloat16* X      = p; p += 2 * BE;         // [t ; a], 64 MB
  __hip_bfloat16* Wt_b   = p; p += 768ull * 1024;
  __hip_bfloat16* Wa_b   = p; p += M1;
  __hip_bfloat16* Wo_b   = p; p += M1;
  __hip_bfloat16* Wvo_b  = p; p += M1;
  __hip_bfloat16* Wg1t_b = p; p += M1;             // Wgt[:, :1024]
  __hip_bfloat16* Wg1a_b = p; p += M1;             // Wga[:, :1024]
  __hip_bfloat16* G2vo   = p; p += 2 * M1;         // [Wgt2.Wvo ; Wga2.Wvo]
  float* bvo  = (float*)p;
  float* bgtp = bvo + 1024;
  float* bgap = bvo + 2048;

  // d_out transient scratch (~64.5 MB, all dead before fused writes f32 out)
  __hip_bfloat16* scr     = (__hip_bfloat16*)d_out;
  __hip_bfloat16* text_b  = scr;                          // 16384x768
  __hip_bfloat16* audio_b = scr + 16384ull * 768;         // 16384x1024
  __hip_bfloat16* WvT_b   = audio_b + BE;                 // Wv^T (bf16)
  __hip_bfloat16* WvoT_b  = WvT_b + M1;                   // Wvo^T (bf16)
  __hip_bfloat16* G2      = WvoT_b + M1;                  // [Wgt2 ; Wga2]

  dim3 blk(256, 1, 1);

  // ---- all f32->bf16 converts in ONE dispatch (9 jobs, 1 block/row) ----
  CvtJobs cj;
  cj.j[0] = { text,       text_b,  768,  768,  192, 0 };
  cj.j[1] = { audio,      audio_b, 1024, 1024, 256, 16384 };
  cj.j[2] = { Wt,         Wt_b,    1024, 1024, 256, 32768 };  // flat 768x1024 view
  cj.j[3] = { Wa,         Wa_b,    1024, 1024, 256, 33536 };
  cj.j[4] = { Wo,         Wo_b,    1024, 1024, 256, 34560 };
  cj.j[5] = { Wgt,        Wg1t_b,  2048, 1024, 256, 35584 };  // Wgt1
  cj.j[6] = { Wgt + 1024, G2,      2048, 1024, 256, 36608 };  // Wgt2
  cj.j[7] = { Wga,        Wg1a_b,  2048, 1024, 256, 37632 };  // Wga1
  cj.j[8] = { Wga + 1024, G2 + M1, 2048, 1024, 256, 38656 };  // Wga2
  cvt9_kernel<<<dim3(39680), blk, 0, stream>>>(cj);
  cvt_t_kernel<<<dim3(32, 32), dim3(32, 8), 0, stream>>>(Wv, WvT_b, 1024, 1024);

  // ---- bias folds (f32) ----
  mv_kernel<<<dim3(256), blk, 0, stream>>>(Wo, 1024, 0, bv, bo, bvo);  // bvo = Wo.bv + bo
  mv2_kernel<<<dim3(256, 2), blk, 0, stream>>>(Wgt, Wga, bvo, bgt, bga, bgtp, bgap);

  // ---- weight folds ----
  GemmJob f1 = { Wo_b, WvT_b, nullptr, Wvo_b, 1024, 1024, 0 };   // Wvo = Wo.Wv
  gemm_bt2_kernel<<<dim3(8, 8), blk, 0, stream>>>(f1, f1, 999);
  tr_bf16_kernel<<<dim3(32, 32), dim3(32, 8), 0, stream>>>(Wvo_b, WvoT_b);
  GemmJob f3 = { G2, WvoT_b, nullptr, G2vo, 1024, 1024, 0 };     // [Wg2.Wvo] stacked
  gemm_bt2_kernel<<<dim3(8, 16), blk, 0, stream>>>(f3, f3, 999);

  // ---- projections (both modalities, one dispatch) ----
  GemmJob pt = { text_b,  Wt_b, bt, X,      768,  1024, 0 };
  GemmJob pa = { audio_b, Wa_b, ba, X + BE, 1024, 1024, 0 };
  gemm_bt2_kernel<<<dim3(8, 256), blk, 0, stream>>>(pt, pa, 128);

  // ---- fused ctx + gate (both modalities, one dispatch, f32 out) ----
  fused_gate_kernel<<<dim3(8, 256), blk, 0, stream>>>(
      X, X + BE, Wg1t_b, Wg1a_b, G2vo, Wvo_b, bgtp, bgap, bvo, out);
}

// Round 6
// 601.530 us; speedup vs baseline: 1.4167x; 1.4167x over previous
//
#include <hip/hip_runtime.h>
#include <hip/hip_bf16.h>

// EmbeddingCrossAttention on MI355X (gfx950). f32 in/out, bf16 MFMA compute.
//
// softmax over single kv slot == 1  =>  ctx = v  =>  everything is affine:
//   t = text@Wt^T+bt ; a = audio@Wa^T+ba
//   t_ctx = a@Wvo^T + bvo            (Wvo = Wo.Wv, bvo = Wo.bv + bo)
//   logit_t = t@Wgt1^T + a@(Wgt2.Wvo)^T + (bgt + Wgt2.bvo)
//   refined_t = g*t + (1-g)*t_ctx, g = sigmoid(logit_t)   (audio swapped)
//
// Round-10 (post-mortem r9: B-direct regressed 285->431 us. Root cause: B
// loads were issued AFTER the A-prefetch; vmcnt is in-order, so consuming
// bfr forced vmcnt(0) -> drained A(t+1) too -> zero pipelining. Rule: what
// you consume must be OLDER than everything you keep in flight.):
//   - REVERT to r8 structure (proven 640 us): all streams LDS-staged.
//   - fused kernel: 3-buffer / ONE barrier per tile (the scheme proven in
//     r8's gemm_bt2). A,B,C each 3-buffered: 24KB/buf, 72KB total. Stage of
//     tile t+1 is one contiguous 4/6-load group; WAITV(4/6) drains exactly
//     tile t, keeps t+1 in flight. Barriers/tile 2 -> 1.
//   - proj + fold1(Wvo) + fold2(WvoT, as a direct GEMM replacing the
//     transpose dispatch) merged into ONE 4-job dispatch (grid 8x272):
//     folds run on CUs idle during the projections. Dispatches 9 -> 7.

typedef __attribute__((ext_vector_type(8))) short short8;
typedef __attribute__((ext_vector_type(4))) float floatx4;

#define WAITV(N) asm volatile("s_waitcnt vmcnt(" #N ")" ::: "memory")
__device__ __forceinline__ void blockbar() {
  asm volatile("" ::: "memory");
  __builtin_amdgcn_s_barrier();
  asm volatile("" ::: "memory");
}

__device__ __forceinline__ float bf2f(__hip_bfloat16 x) { return __bfloat162float(x); }

__device__ __forceinline__ void gl_lds16(const void* g, void* l) {
  __builtin_amdgcn_global_load_lds(
      (const __attribute__((address_space(1))) unsigned int*)g,
      (__attribute__((address_space(3))) unsigned int*)l,
      16, 0, 0);
}

// XCD-aware block swizzle: same-m blocks share lid%8 -> same XCD, 8 lids apart
// -> A-tile stays L2-resident across its n-sweep (FETCH 148 vs 291 MB without).
__device__ __forceinline__ void swizzle_mn(int& m_idx, int& n_idx) {
  const int lid = blockIdx.y * 8 + blockIdx.x;
  m_idx = (lid >> 6) * 8 + (lid & 7);
  n_idx = (lid >> 3) & 7;
}

// ---- 9-job strided f32 -> bf16 convert; 1 block per row ----
struct CvtJob { const float* src; __hip_bfloat16* dst; int sld, dld, cols4, rowbase; };
struct CvtJobs { CvtJob j[9]; };

__global__ __launch_bounds__(256)
void cvt9_kernel(CvtJobs a) {
  const int r = blockIdx.x;
  int ji = 0;
#pragma unroll
  for (int i = 1; i < 9; ++i) ji += (r >= a.j[i].rowbase) ? 1 : 0;
  const CvtJob J = a.j[ji];
  const int rr = r - J.rowbase;
  const int c4 = threadIdx.x;
  if (c4 >= J.cols4) return;
  const float4 v = *(const float4*)(J.src + (size_t)rr * J.sld + c4 * 4);
  union { __hip_bfloat16 h[4]; uint2 u; } o;
  o.h[0] = __float2bfloat16(v.x);
  o.h[1] = __float2bfloat16(v.y);
  o.h[2] = __float2bfloat16(v.z);
  o.h[3] = __float2bfloat16(v.w);
  *(uint2*)(J.dst + (size_t)rr * J.dld + c4 * 4) = o.u;
}

// Transposed convert: dst[c][r] = bf16(src[r][c]), R=C=1024 (f32 in).
__global__ __launch_bounds__(256)
void cvt_t_kernel(const float* __restrict__ src, __hip_bfloat16* __restrict__ dst,
                  int R, int C) {
  __shared__ float tile[32][33];
  const int tx = threadIdx.x, ty = threadIdx.y;  // block (32, 8)
  const int bx = blockIdx.x * 32, by = blockIdx.y * 32;
#pragma unroll
  for (int i = 0; i < 32; i += 8)
    tile[ty + i][tx] = src[(size_t)(by + ty + i) * C + bx + tx];
  __syncthreads();
#pragma unroll
  for (int i = 0; i < 32; i += 8)
    dst[(size_t)(bx + ty + i) * R + by + tx] = __float2bfloat16(tile[tx][ty + i]);
}

// y[r] = sum_k W[r*ld + coff + k] * x[k] + b[r],  K = 1024. 4 rows/block.
__global__ __launch_bounds__(256)
void mv_kernel(const float* __restrict__ W, int ld, int coff,
               const float* __restrict__ x, const float* __restrict__ b,
               float* __restrict__ y) {
  const int lane = threadIdx.x & 63;
  const int row = blockIdx.x * 4 + (threadIdx.x >> 6);
  float acc = 0.f;
  for (int k = lane; k < 1024; k += 64)
    acc += W[(size_t)row * ld + coff + k] * x[k];
#pragma unroll
  for (int off = 32; off > 0; off >>= 1) acc += __shfl_down(acc, off);
  if (lane == 0) y[row] = acc + b[row];
}

// Two mv jobs in one launch (both ld=2048, coff=1024, x=bvo). blockIdx.y picks.
__global__ __launch_bounds__(256)
void mv2_kernel(const float* __restrict__ W0, const float* __restrict__ W1,
                const float* __restrict__ x,
                const float* __restrict__ b0, const float* __restrict__ b1,
                float* __restrict__ y0, float* __restrict__ y1) {
  const float* W = blockIdx.y ? W1 : W0;
  const float* b = blockIdx.y ? b1 : b0;
  float* y = blockIdx.y ? y1 : y0;
  const int lane = threadIdx.x & 63;
  const int row = blockIdx.x * 4 + (threadIdx.x >> 6);
  float acc = 0.f;
  for (int k = lane; k < 1024; k += 64)
    acc += W[(size_t)row * 2048 + 1024 + k] * x[k];
#pragma unroll
  for (int off = 32; off > 0; off >>= 1) acc += __shfl_down(acc, off);
  if (lane == 0) y[row] = acc + b[row];
}

// C = A @ W^T (+bias), bf16 out. Up to 4 jobs split on m_idx (cuts c1<=c2<=c3).
// BK=32, 3-buffer LDS, ONE barrier per K-tile, counted vmcnt (never 0 in
// steady state). K%32==0, K/32>=2.
struct GemmJob {
  const __hip_bfloat16* A; const __hip_bfloat16* W;
  const float* bias; __hip_bfloat16* C; int K; int ldc; int coff;
};

__global__ __launch_bounds__(256)
void gemm_bt4_kernel(GemmJob j0, GemmJob j1, GemmJob j2, GemmJob j3,
                     int c1, int c2, int c3) {
  constexpr int BK = 32;
  __shared__ __align__(16) __hip_bfloat16 lA[3 * 128 * BK];
  __shared__ __align__(16) __hip_bfloat16 lB[3 * 128 * BK];

  const int tid  = threadIdx.x;
  const int lane = tid & 63;
  const int wave = tid >> 6;
  const int wm = wave & 1;
  const int wn = wave >> 1;
  int m_idx, n_idx;
  swizzle_mn(m_idx, n_idx);
  GemmJob J; int mb;
  if (m_idx < c1)      { J = j0; mb = m_idx; }
  else if (m_idx < c2) { J = j1; mb = m_idx - c1; }
  else if (m_idx < c3) { J = j2; mb = m_idx - c2; }
  else                 { J = j3; mb = m_idx - c3; }
  const int m0 = mb * 128;
  const int n0 = n_idx * 128;
  const int K = J.K;

  floatx4 acc[4][4];
#pragma unroll
  for (int i = 0; i < 4; ++i)
#pragma unroll
    for (int j = 0; j < 4; ++j) {
      floatx4 z = {0.f, 0.f, 0.f, 0.f};
      acc[i][j] = z;
    }

  const int srow  = tid >> 2;
  const int sc_sw = ((tid & 3) ^ (srow & 3)) * 8;
  const int fr = lane & 15;
  const int fqs = (((lane >> 4) ^ (fr & 3))) * 8;

  const __hip_bfloat16* pA = J.A + (size_t)(m0 + srow) * K + sc_sw;
  const __hip_bfloat16* pW = J.W + (size_t)(n0 + srow) * K + sc_sw;
  const size_t SR = (size_t)64 * K;

  int sOff = 0;
  auto stageAB = [&]() {
    gl_lds16(pA,      (char*)lA + sOff + tid * 16);
    gl_lds16(pA + SR, (char*)lA + sOff + 4096 + tid * 16);
    gl_lds16(pW,      (char*)lB + sOff + tid * 16);
    gl_lds16(pW + SR, (char*)lB + sOff + 4096 + tid * 16);
    pA += BK; pW += BK;
    sOff = (sOff == 16384) ? 0 : sOff + 8192;
  };

  int cOff = 0;
  auto compute = [&]() {
    const short* sA = (const short*)((const char*)lA + cOff);
    const short* sB = (const short*)((const char*)lB + cOff);
    short8 af[4], bfr[4];
#pragma unroll
    for (int i = 0; i < 4; ++i)
      af[i] = *(const short8*)(sA + (wm * 64 + i * 16 + fr) * BK + fqs);
#pragma unroll
    for (int j = 0; j < 4; ++j)
      bfr[j] = *(const short8*)(sB + (wn * 64 + j * 16 + fr) * BK + fqs);
#pragma unroll
    for (int i = 0; i < 4; ++i)
#pragma unroll
      for (int j = 0; j < 4; ++j)
        acc[i][j] = __builtin_amdgcn_mfma_f32_16x16x32_bf16(af[i], bfr[j], acc[i][j], 0, 0, 0);
    cOff = (cOff == 16384) ? 0 : cOff + 8192;
  };

  const int NT = K / BK;
  stageAB();                      // tile 0 -> buf 0
  for (int t = 0; t < NT - 1; ++t) {
    stageAB();                    // tile t+1 -> buf (t+1)%3
    WAITV(4);                     // drain tile t; keep t+1 in flight
    blockbar();                   // single barrier per tile
    compute();
  }
  WAITV(0);
  blockbar();
  compute();

  const int col = lane & 15;
  const int rq  = (lane >> 4) * 4;
#pragma unroll
  for (int j = 0; j < 4; ++j) {
    const int n = n0 + wn * 64 + j * 16 + col;
    const float bv = J.bias ? J.bias[n] : 0.f;
#pragma unroll
    for (int i = 0; i < 4; ++i)
#pragma unroll
      for (int r = 0; r < 4; ++r) {
        const int m = m0 + wm * 64 + i * 16 + rq + r;
        J.C[(size_t)m * J.ldc + J.coff + n] = __float2bfloat16(acc[i][j][r] + bv);
      }
  }
}

// Fused ctx + gate, BOTH modalities in one dispatch (m_idx >= 128 -> audio):
//   phase 1 (32 tiles): accL += Xs @ Wg1^T
//   phase 2 (32 tiles): accL += Xo @ Wg2vo^T ; accC += Xo @ Wvo^T
//   out[m,n] = g*Xs[m,n] + (1-g)*(accC+bvo),  g = sigmoid(accL+bg)
// A,B,C all LDS-staged, 3 buffers x 24KB (A|B|C 8KB each), ONE barrier/tile,
// counted vmcnt: stage group of tile t+1 (4 or 6 loads) stays in flight.
__global__ __launch_bounds__(256)
void fused_gate_kernel(const __hip_bfloat16* __restrict__ Xt,
                       const __hip_bfloat16* __restrict__ Xa,
                       const __hip_bfloat16* __restrict__ Wg1t,
                       const __hip_bfloat16* __restrict__ Wg1a,
                       const __hip_bfloat16* __restrict__ G2vo,   // 2048 x 1024
                       const __hip_bfloat16* __restrict__ Wvo,    // 1024 x 1024
                       const float* __restrict__ bgt,
                       const float* __restrict__ bga,
                       const float* __restrict__ bvo,
                       float* __restrict__ out) {
  constexpr int BK = 32;
  constexpr int BUF = 24576;                        // bytes per buffer (A|B|C)
  __shared__ __align__(16) __hip_bfloat16 lds[3 * 12288];   // 72 KB

  const int tid  = threadIdx.x;
  const int lane = tid & 63;
  const int wave = tid >> 6;
  const int wm = wave & 1;
  const int wn = wave >> 1;
  int m_idx, n_idx;
  swizzle_mn(m_idx, n_idx);
  const bool aud = m_idx >= 128;
  const int m0 = (m_idx & 127) * 128;
  const int n0 = n_idx * 128;

  const size_t M1 = 1024ull * 1024;
  const __hip_bfloat16* Xs  = aud ? Xa : Xt;
  const __hip_bfloat16* Xo  = aud ? Xt : Xa;
  const __hip_bfloat16* Wg1 = aud ? Wg1a : Wg1t;
  const __hip_bfloat16* Wg2vo = G2vo + (aud ? M1 : 0);
  const float* bg = aud ? bga : bgt;
  float* po = out + (aud ? (size_t)16384 * 1024 : 0);

  floatx4 accL[4][4], accC[4][4];
#pragma unroll
  for (int i = 0; i < 4; ++i)
#pragma unroll
    for (int j = 0; j < 4; ++j) {
      floatx4 z = {0.f, 0.f, 0.f, 0.f};
      accL[i][j] = z;
      accC[i][j] = z;
    }

  const int srow  = tid >> 2;
  const int sc_sw = ((tid & 3) ^ (srow & 3)) * 8;
  const int fr = lane & 15;
  const int fqs = (((lane >> 4) ^ (fr & 3))) * 8;

  const __hip_bfloat16* pAs = Xs    + (size_t)(m0 + srow) * 1024 + sc_sw;
  const __hip_bfloat16* pB1 = Wg1   + (size_t)(n0 + srow) * 1024 + sc_sw;
  const __hip_bfloat16* pAo = Xo    + (size_t)(m0 + srow) * 1024 + sc_sw;
  const __hip_bfloat16* pB2 = Wg2vo + (size_t)(n0 + srow) * 1024 + sc_sw;
  const __hip_bfloat16* pBv = Wvo   + (size_t)(n0 + srow) * 1024 + sc_sw;
  const size_t SR = (size_t)64 * 1024;

  int sOff = 0, cOff = 0;
  auto stage1 = [&]() {               // 4 loads: A | B
    gl_lds16(pAs,      (char*)lds + sOff + tid * 16);
    gl_lds16(pAs + SR, (char*)lds + sOff + 4096 + tid * 16);
    gl_lds16(pB1,      (char*)lds + sOff + 8192 + tid * 16);
    gl_lds16(pB1 + SR, (char*)lds + sOff + 12288 + tid * 16);
    pAs += BK; pB1 += BK;
    sOff = (sOff == 2 * BUF) ? 0 : sOff + BUF;
  };
  auto stage2 = [&]() {               // 6 loads: A | B | C
    gl_lds16(pAo,      (char*)lds + sOff + tid * 16);
    gl_lds16(pAo + SR, (char*)lds + sOff + 4096 + tid * 16);
    gl_lds16(pB2,      (char*)lds + sOff + 8192 + tid * 16);
    gl_lds16(pB2 + SR, (char*)lds + sOff + 12288 + tid * 16);
    gl_lds16(pBv,      (char*)lds + sOff + 16384 + tid * 16);
    gl_lds16(pBv + SR, (char*)lds + sOff + 20480 + tid * 16);
    pAo += BK; pB2 += BK; pBv += BK;
    sOff = (sOff == 2 * BUF) ? 0 : sOff + BUF;
  };

  auto comp1 = [&]() {
    const short* sA = (const short*)((const char*)lds + cOff);
    const short* sB = (const short*)((const char*)lds + cOff + 8192);
    short8 af[4], bfr[4];
#pragma unroll
    for (int i = 0; i < 4; ++i)
      af[i] = *(const short8*)(sA + (wm * 64 + i * 16 + fr) * BK + fqs);
#pragma unroll
    for (int j = 0; j < 4; ++j)
      bfr[j] = *(const short8*)(sB + (wn * 64 + j * 16 + fr) * BK + fqs);
#pragma unroll
    for (int i = 0; i < 4; ++i)
#pragma unroll
      for (int j = 0; j < 4; ++j)
        accL[i][j] = __builtin_amdgcn_mfma_f32_16x16x32_bf16(af[i], bfr[j], accL[i][j], 0, 0, 0);
    cOff = (cOff == 2 * BUF) ? 0 : cOff + BUF;
  };
  auto comp2 = [&]() {
    const short* sA = (const short*)((const char*)lds + cOff);
    const short* sB = (const short*)((const char*)lds + cOff + 8192);
    const short* sC = (const short*)((const char*)lds + cOff + 16384);
    short8 af[4], bfr[4], cfr[4];
#pragma unroll
    for (int i = 0; i < 4; ++i)
      af[i] = *(const short8*)(sA + (wm * 64 + i * 16 + fr) * BK + fqs);
#pragma unroll
    for (int j = 0; j < 4; ++j) {
      bfr[j] = *(const short8*)(sB + (wn * 64 + j * 16 + fr) * BK + fqs);
      cfr[j] = *(const short8*)(sC + (wn * 64 + j * 16 + fr) * BK + fqs);
    }
#pragma unroll
    for (int i = 0; i < 4; ++i)
#pragma unroll
      for (int j = 0; j < 4; ++j) {
        accL[i][j] = __builtin_amdgcn_mfma_f32_16x16x32_bf16(af[i], bfr[j], accL[i][j], 0, 0, 0);
        accC[i][j] = __builtin_amdgcn_mfma_f32_16x16x32_bf16(af[i], cfr[j], accC[i][j], 0, 0, 0);
      }
    cOff = (cOff == 2 * BUF) ? 0 : cOff + BUF;
  };

  // phase 1: tiles 0..31 (tile t lives in buf t%3)
  stage1();                            // tile 0
  for (int t = 0; t < 31; ++t) {
    stage1();                          // tile t+1 (4 loads in flight)
    WAITV(4);                          // drain tile t
    blockbar();
    comp1();                           // tile t
  }
  // boundary: prefetch first phase-2 tile, then finish last phase-1 tile
  stage2();                            // tile 32 (6 loads in flight)
  WAITV(6);                            // drain tile 31
  blockbar();
  comp1();                             // tile 31
  // phase 2: tiles 32..62
  for (int t = 0; t < 31; ++t) {
    stage2();                          // tile t+1
    WAITV(6);                          // drain tile t
    blockbar();
    comp2();                           // tile t
  }
  WAITV(0);
  blockbar();
  comp2();                             // tile 63

  // epilogue: D mapping col = lane&15, row = (lane>>4)*4 + reg
  const int col = lane & 15;
  const int rq  = (lane >> 4) * 4;
#pragma unroll
  for (int j = 0; j < 4; ++j) {
    const int n = n0 + wn * 64 + j * 16 + col;
    const float bgv = bg[n];
    const float bcv = bvo[n];
#pragma unroll
    for (int i = 0; i < 4; ++i)
#pragma unroll
      for (int r = 0; r < 4; ++r) {
        const int m = m0 + wm * 64 + i * 16 + rq + r;
        const size_t idx = (size_t)m * 1024 + n;
        const float lg = accL[i][j][r] + bgv;
        const float cv = accC[i][j][r] + bcv;
        const float xv = bf2f(Xs[idx]);
        const float g = 1.f / (1.f + __expf(-lg));
        po[idx] = g * xv + (1.f - g) * cv;
      }
  }
}

extern "C" void kernel_launch(void* const* d_in, const int* in_sizes, int n_in,
                              void* d_out, int out_size, void* d_ws, size_t ws_size,
                              hipStream_t stream) {
  (void)in_sizes; (void)n_in; (void)out_size; (void)ws_size;

  const float* text  = (const float*)d_in[0];
  const float* audio = (const float*)d_in[1];
  const float* Wt  = (const float*)d_in[2];
  const float* bt  = (const float*)d_in[3];
  const float* Wa  = (const float*)d_in[4];
  const float* ba  = (const float*)d_in[5];
  // d_in[6..9] = Wq,bq,Wk,bk: dead (softmax over single kv slot == 1)
  const float* Wv  = (const float*)d_in[10];
  const float* bv  = (const float*)d_in[11];
  const float* Wo  = (const float*)d_in[12];
  const float* bo  = (const float*)d_in[13];
  const float* Wgt = (const float*)d_in[14];
  const float* bgt = (const float*)d_in[15];
  const float* Wga = (const float*)d_in[16];
  const float* bga = (const float*)d_in[17];

  const size_t BE = 16384ull * 1024;
  const size_t M1 = 1024ull * 1024;
  float* out = (float*)d_out;

  // ws (persistent): ~79.5 MB (< 92 MB proven-safe budget)
  __hip_bfloat16* p = (__hip_bfloat16*)d_ws;
  __hip_bfloat16* X      = p; p += 2 * BE;         // [t ; a], 64 MB
  __hip_bfloat16* Wt_b   = p; p += 768ull * 1024;
  __hip_bfloat16* Wa_b   = p; p += M1;
  __hip_bfloat16* Wo_b   = p; p += M1;
  __hip_bfloat16* Wvo_b  = p; p += M1;
  __hip_bfloat16* Wg1t_b = p; p += M1;             // Wgt[:, :1024]
  __hip_bfloat16* Wg1a_b = p; p += M1;             // Wga[:, :1024]
  __hip_bfloat16* G2vo   = p; p += 2 * M1;         // [Wgt2.Wvo ; Wga2.Wvo]
  float* bvo  = (float*)p;
  float* bgtp = bvo + 1024;
  float* bgap = bvo + 2048;

  // d_out transient scratch (~64.5 MB, all dead before fused writes f32 out)
  __hip_bfloat16* scr     = (__hip_bfloat16*)d_out;
  __hip_bfloat16* text_b  = scr;                          // 16384x768
  __hip_bfloat16* audio_b = scr + 16384ull * 768;         // 16384x1024
  __hip_bfloat16* WvT_b   = audio_b + BE;                 // Wv^T (bf16)
  __hip_bfloat16* WvoT_b  = WvT_b + M1;                   // Wvo^T (bf16)
  __hip_bfloat16* G2      = WvoT_b + M1;                  // [Wgt2 ; Wga2]

  dim3 blk(256, 1, 1);

  // ---- all f32->bf16 converts in ONE dispatch (9 jobs, 1 block/row) ----
  CvtJobs cj;
  cj.j[0] = { text,       text_b,  768,  768,  192, 0 };
  cj.j[1] = { audio,      audio_b, 1024, 1024, 256, 16384 };
  cj.j[2] = { Wt,         Wt_b,    1024, 1024, 256, 32768 };  // flat 768x1024 view
  cj.j[3] = { Wa,         Wa_b,    1024, 1024, 256, 33536 };
  cj.j[4] = { Wo,         Wo_b,    1024, 1024, 256, 34560 };
  cj.j[5] = { Wgt,        Wg1t_b,  2048, 1024, 256, 35584 };  // Wgt1
  cj.j[6] = { Wgt + 1024, G2,      2048, 1024, 256, 36608 };  // Wgt2
  cj.j[7] = { Wga,        Wg1a_b,  2048, 1024, 256, 37632 };  // Wga1
  cj.j[8] = { Wga + 1024, G2 + M1, 2048, 1024, 256, 38656 };  // Wga2
  cvt9_kernel<<<dim3(39680), blk, 0, stream>>>(cj);
  cvt_t_kernel<<<dim3(32, 32), dim3(32, 8), 0, stream>>>(Wv, WvT_b, 1024, 1024);

  // ---- bias folds (f32) ----
  mv_kernel<<<dim3(256), blk, 0, stream>>>(Wo, 1024, 0, bv, bo, bvo);  // bvo = Wo.bv + bo
  mv2_kernel<<<dim3(256, 2), blk, 0, stream>>>(Wgt, Wga, bvo, bgt, bga, bgtp, bgap);

  // ---- projections + Wvo folds, ONE dispatch (4 jobs on m_idx) ----
  // jobs: [0,128): text proj  [128,256): audio proj
  //       [256,264): Wvo = Wo.Wv   [264,272): WvoT[k,n] = sum_m WvT[k,m] Wo[n,m]
  GemmJob pt = { text_b,  Wt_b,  bt,      X,       768,  1024, 0 };
  GemmJob pa = { audio_b, Wa_b,  ba,      X + BE,  1024, 1024, 0 };
  GemmJob f1 = { Wo_b,    WvT_b, nullptr, Wvo_b,   1024, 1024, 0 };
  GemmJob f2 = { WvT_b,   Wo_b,  nullptr, WvoT_b,  1024, 1024, 0 };
  gemm_bt4_kernel<<<dim3(8, 272), blk, 0, stream>>>(pt, pa, f1, f2, 128, 256, 264);

  // ---- G2vo[m,n] = sum_k G2[m,k] WvoT[n,k] = (Wg2.Wvo)[m,n], stacked ----
  GemmJob f3 = { G2, WvoT_b, nullptr, G2vo, 1024, 1024, 0 };
  gemm_bt4_kernel<<<dim3(8, 16), blk, 0, stream>>>(f3, f3, f3, f3, 999, 999, 999);

  // ---- fused ctx + gate (both modalities, one dispatch, f32 out) ----
  fused_gate_kernel<<<dim3(8, 256), blk, 0, stream>>>(
      X, X + BE, Wg1t_b, Wg1a_b, G2vo, Wvo_b, bgtp, bgap, bvo, out);
}